// Round 14
// baseline (76.374 us; speedup 1.0000x reference)
//
#include <hip/hip_runtime.h>

typedef __attribute__((ext_vector_type(8))) short bf16x8;
typedef __attribute__((ext_vector_type(4))) float f32x4;

#define SP 8192
#define INF 256
#define HID 64
#define NEG 0.2f

__device__ __forceinline__ unsigned bf16r(float x) {
    unsigned u = __float_as_uint(x);
    return (u + 0x7FFFu + ((u >> 16) & 1u)) >> 16;
}

// ---------------- Kernel A: projection + LeakyReLU + sumsq + bf16 hi/lo split
// 1024 blocks x 16 rows, 32 KB LDS -> 4 blocks/CU. w staged in two 32 KB
// halves. F rows 0..8191 = input1, 8192..16383 = input2, MFMA-fragment order:
//   element (row,k) -> flat = ((R*2+s)*64 + lfr)*8 + (k&7)
//   R=row>>4, s=k>>5, lfr=(row&15)|(((k>>3)&3)<<4)
__global__ __launch_bounds__(256, 4) void proj_kernel(
    const float* __restrict__ in1, const float* __restrict__ in2,
    const float* __restrict__ w,
    unsigned short* __restrict__ Fhi, unsigned short* __restrict__ Flo,
    float* __restrict__ SQ)
{
    __shared__ float sbuf[128 * HID];   // 32 KB: one half of w

    int bid = blockIdx.x;
    int tid = threadIdx.x;
    const float* rowbase = ((bid < 512) ? in1 : in2) + (long)(bid & 511) * 16 * INF;
    int r  = tid >> 4;          // 16 rows per block, 16 threads per row
    int c0 = (tid & 15) * 4;    // 4 consecutive output cols per thread

    float acc[4] = {0.f, 0.f, 0.f, 0.f};
    #pragma unroll 1
    for (int half = 0; half < 2; half++) {
        const float4* w4 = (const float4*)(w + half * 128 * HID);
        float4* s4 = (float4*)sbuf;
        #pragma unroll
        for (int i = 0; i < 8; i++) s4[tid + 256 * i] = w4[tid + 256 * i];
        __syncthreads();

        const float* arow = rowbase + r * INF + half * 128;
        #pragma unroll 4
        for (int k = 0; k < 128; k += 4) {
            float4 av = *(const float4*)(arow + k);
            #pragma unroll
            for (int kk = 0; kk < 4; kk++) {
                float a = (kk == 0) ? av.x : (kk == 1) ? av.y
                        : (kk == 2) ? av.z : av.w;
                float4 wv = *(const float4*)(sbuf + (k + kk) * HID + c0);
                acc[0] = fmaf(a, wv.x, acc[0]);
                acc[1] = fmaf(a, wv.y, acc[1]);
                acc[2] = fmaf(a, wv.z, acc[2]);
                acc[3] = fmaf(a, wv.w, acc[3]);
            }
        }
        __syncthreads();
    }

    float ss = 0.f;
    #pragma unroll
    for (int j = 0; j < 4; j++) {
        float v = acc[j];
        v = (v > 0.f) ? v : NEG * v;
        acc[j] = v;
        ss = fmaf(v, v, ss);
    }
    #pragma unroll
    for (int msk = 1; msk < 16; msk <<= 1) ss += __shfl_xor(ss, msk, 64);

    int grow = bid * 16 + r;
    if ((tid & 15) == 0) SQ[grow] = ss;

    int s  = c0 >> 5;
    int g  = (c0 >> 3) & 3;
    int jb = c0 & 7;
    int R   = grow >> 4;
    int lfr = (grow & 15) | (g << 4);
    long fi = ((long)((R * 2 + s) * 64 + lfr)) * 8 + jb;
    ushort4 hv, lv;
    unsigned short* ph = (unsigned short*)&hv;
    unsigned short* pl = (unsigned short*)&lv;
    #pragma unroll
    for (int j = 0; j < 4; j++) {
        float v = acc[j];
        unsigned hb = bf16r(v);
        float hf = __uint_as_float(hb << 16);
        unsigned lb = bf16r(v - hf);
        ph[j] = (unsigned short)hb;
        pl[j] = (unsigned short)lb;
    }
    *(ushort4*)(Fhi + fi) = hv;
    *(ushort4*)(Flo + fi) = lv;
}

// light barrier: orders LDS traffic only (lgkmcnt), does NOT drain the
// global-store queue (vmcnt) like __syncthreads would.
__device__ __forceinline__ void lds_barrier() {
    asm volatile("s_waitcnt lgkmcnt(0)" ::: "memory");
    __builtin_amdgcn_s_barrier();
    asm volatile("" ::: "memory");
}

// async global->LDS DMA, 16 B/lane: LDS dest = uniform base + lane*16,
// global src is per-lane.
__device__ __forceinline__ void dma16(const unsigned short* g, unsigned short* l) {
    __builtin_amdgcn_global_load_lds(
        (const __attribute__((address_space(1))) unsigned int*)g,
        (__attribute__((address_space(3))) unsigned int*)l, 16, 0, 0);
}

// ---------------- Kernel B: pairwise, 256x256 tiles, bf16x3 MFMA.
// A-fragments now arrive via a 2-slot global_load_lds DMA ring (prefetched
// one phase ahead; each of the 4 waves DMAs one (plane,s) 1 KB quarter) --
// removes the per-phase L2 load latency from the critical path and the 4x
// redundant per-wave A reads. vmcnt bookkeeping: DMA issued BEFORE the 4
// stores; in-order retirement => s_waitcnt vmcnt(4) before the barrier
// guarantees DMA landed without draining the stores.
__global__ __launch_bounds__(256, 4) void pair_kernel(
    const unsigned short* __restrict__ Fhi, const unsigned short* __restrict__ Flo,
    const float* __restrict__ SQ, float* __restrict__ out)
{
    __shared__ float lds[2][16][256];                 // 32 KB result dbuf
    __shared__ unsigned short Abuf[2][2][2][512];     // 8 KB A ring [slot][plane][s]

    int bid = blockIdx.x;
    int xcd = bid & 7;
    int kk = bid >> 3;
    int tc = xcd * 4 + (kk >> 5);     // 4 tile-columns per XCD
    int tr = kk & 31;                 // rows swept fastest (B-panel reuse)
    int lane = threadIdx.x & 63;
    int wave = threadIdx.x >> 6;
    int row0 = tr * 256;
    int col0 = tc * 256;
    int wcol0 = col0 + wave * 64;

    const bf16x8* FhiV = (const bf16x8*)Fhi;
    const bf16x8* FloV = (const bf16x8*)Flo;

    int RA0 = tr * 16;
    int RB0 = 512 + tc * 16 + wave * 4;   // f2 region: R base 512

    // col (f2) fragments: 4 n x 2 s, both planes (64 VGPRs), held all phases
    bf16x8 bh[2][4], bl[2][4];
    #pragma unroll
    for (int s = 0; s < 2; s++)
        #pragma unroll
        for (int n = 0; n < 4; n++) {
            int fi = ((RB0 + n) * 2 + s) * 64 + lane;
            bh[s][n] = FhiV[fi];
            bl[s][n] = FloV[fi];
        }

    const float C2 = 2.081368898419084f;      // (log2 e)^2
    float sqb[4];
    #pragma unroll
    for (int n = 0; n < 4; n++) sqb[n] = SQ[SP + wcol0 + 16 * n + (lane & 15)] * C2;

    int rbase = (lane >> 4) * 4;
    int swz = (lane & 16);            // == (row&4)<<2 for rows rbase..rbase+3
    int start = (bid * 5) & 15;       // phase skew (de-convoy)
    int mprev = 0;

    // this wave's DMA quarter: plane = wave>>1, s = wave&1
    int dp = wave >> 1, dsl = wave & 1;
    const unsigned short* dsrc_base = (dp ? Flo : Fhi);

    // prologue: DMA phase-0 A into slot 0, wait, barrier
    {
        int m0 = start;
        const unsigned short* g = dsrc_base + ((long)((RA0 + m0) * 2 + dsl) * 64 + lane) * 8;
        dma16(g, &Abuf[0][dp][dsl][0]);
        asm volatile("s_waitcnt vmcnt(0)" ::: "memory");
        lds_barrier();
    }

    #pragma unroll 1
    for (int mi = 0; mi < 16; mi++) {
        int m = (mi + start) & 15;
        int buf = mi & 1;
        int slot = mi & 1;

        // 1. issue next phase's A DMA (into slot^1) FIRST
        if (mi < 15) {
            int mn = (mi + 1 + start) & 15;
            const unsigned short* g = dsrc_base + ((long)((RA0 + mn) * 2 + dsl) * 64 + lane) * 8;
            dma16(g, &Abuf[slot ^ 1][dp][dsl][0]);
        }

        // 2. read this phase's A from LDS ring (ds_read_b128, ~120 cy)
        bf16x8 ah[2], al[2];
        #pragma unroll
        for (int s = 0; s < 2; s++) {
            ah[s] = *(const bf16x8*)&Abuf[slot][0][s][lane * 8];
            al[s] = *(const bf16x8*)&Abuf[slot][1][s][lane * 8];
        }

        // 3. trailing store of phase mi-1 from result buf^1 (1 KB contiguous)
        if (mi > 0) {
            #pragma unroll
            for (int j = 0; j < 4; j++) {
                int r = wave * 4 + j;
                int rs = (r & 4) << 2;
                f32x4 vv = *(const f32x4*)&lds[buf ^ 1][r][(lane * 4) ^ rs];
                *(f32x4*)(out + (long)(row0 + 16 * mprev + r) * SP + col0 + lane * 4) = vv;
            }
        }

        // 4. MFMA
        f32x4 acc[4];
        #pragma unroll
        for (int n = 0; n < 4; n++) acc[n] = (f32x4){0.f, 0.f, 0.f, 0.f};
        #pragma unroll
        for (int s = 0; s < 2; s++)
            #pragma unroll
            for (int n = 0; n < 4; n++) {
                acc[n] = __builtin_amdgcn_mfma_f32_16x16x32_bf16(ah[s], bh[s][n], acc[n], 0, 0, 0);
                acc[n] = __builtin_amdgcn_mfma_f32_16x16x32_bf16(ah[s], bl[s][n], acc[n], 0, 0, 0);
                acc[n] = __builtin_amdgcn_mfma_f32_16x16x32_bf16(al[s], bh[s][n], acc[n], 0, 0, 0);
            }

        // 5. epilogue -> result LDS buf (swizzled)
        // q=(sq1+sq2-2dot)*log2e^2; d'=sqrt(q)=dist*log2e
        // y=exp2(-d')=e^-dist; sigmoid(-dist) ~= y-y^2 (err<=y^3<=4.5e-6)
        float4 t = *(const float4*)(SQ + row0 + 16 * m + rbase);
        float sa[4] = {t.x * C2, t.y * C2, t.z * C2, t.w * C2};
        #pragma unroll
        for (int n = 0; n < 4; n++) {
            int colb = (wave * 64 + 16 * n + (lane & 15)) ^ swz;
            #pragma unroll
            for (int v = 0; v < 4; v++) {
                float q = fmaf(acc[n][v], -2.f * C2, sa[v] + sqb[n]);
                q = fmaxf(q, 0.f);
                float d = __builtin_amdgcn_sqrtf(q);
                float y = __builtin_amdgcn_exp2f(-d);
                lds[buf][rbase + v][colb] = fmaf(-y, y, y);
            }
        }

        // 6. ensure next-phase DMA landed (without draining the stores:
        //    DMA was issued before this phase's stores; in-order retirement
        //    means vmcnt(4) = DMA retired, 4 stores may remain in flight).
        if (mi == 0) {
            asm volatile("s_waitcnt vmcnt(0)" ::: "memory");
        } else {
            asm volatile("s_waitcnt vmcnt(4)" ::: "memory");
        }
        lds_barrier();
        mprev = m;
    }

    // tail: store the last phase's tile (buf index 1)
    #pragma unroll
    for (int j = 0; j < 4; j++) {
        int r = wave * 4 + j;
        int rs = (r & 4) << 2;
        f32x4 vv = *(const f32x4*)&lds[1][r][(lane * 4) ^ rs];
        *(f32x4*)(out + (long)(row0 + 16 * mprev + r) * SP + col0 + lane * 4) = vv;
    }
}

extern "C" void kernel_launch(void* const* d_in, const int* in_sizes, int n_in,
                              void* d_out, int out_size, void* d_ws, size_t ws_size,
                              hipStream_t stream)
{
    const float* in1 = (const float*)d_in[0];
    const float* in2 = (const float*)d_in[1];
    const float* w   = (const float*)d_in[2];
    float* out = (float*)d_out;
    char* ws = (char*)d_ws;
    unsigned short* Fhi = (unsigned short*)ws;                       // 2 MB
    unsigned short* Flo = (unsigned short*)(ws + 2u * 1024 * 1024);  // 2 MB
    float* SQ = (float*)(ws + 4u * 1024 * 1024);                     // 64 KB

    hipLaunchKernelGGL(proj_kernel, dim3(1024), dim3(256), 0, stream,
                       in1, in2, w, Fhi, Flo, SQ);
    hipLaunchKernelGGL(pair_kernel, dim3(1024), dim3(256), 0, stream,
                       Fhi, Flo, SQ, out);
}